// Round 3
// baseline (184.049 us; speedup 1.0000x reference)
//
#include <hip/hip_runtime.h>
#include <hip/hip_fp16.h>

typedef _Float16 half8 __attribute__((ext_vector_type(8)));
typedef _Float16 half4 __attribute__((ext_vector_type(4)));
typedef float floatx4 __attribute__((ext_vector_type(4)));

#define T_SEQ 2048
#define NB    8

// ---------------------------------------------------------------------------
// Kernel 0: prep — WqT f16 [64][768] and bias*log2e table [4095]
// ---------------------------------------------------------------------------
__global__ __launch_bounds__(256) void prep_kernel(
    const float* __restrict__ Wq, const float* __restrict__ rel,
    _Float16* __restrict__ WqT, float* __restrict__ biasS)
{
  const int bid = blockIdx.x, tid = threadIdx.x;
  if (bid < 64) {
    for (int k = tid; k < 768; k += 256)
      WqT[bid * 768 + k] = (_Float16)Wq[k * 64 + bid];
  } else {
    for (int i = tid; i < 4095; i += 256)
      biasS[i] = rel[i] * 1.44269504f;
  }
}

// ---------------------------------------------------------------------------
// Kernel 1: q = x @ Wq. 1024 blocks x 256 threads; 16 rows/block;
// K split across 4 waves (192 each, 6 MFMA iters); LDS combine.
// Also emits per-row softmax offset Ct = (|q_t|^2/8)*log2e + bias0 + 8.
// ---------------------------------------------------------------------------
__global__ __launch_bounds__(256, 4) void qproj_kernel(
    const float* __restrict__ x, const _Float16* __restrict__ WqT,
    const float* __restrict__ biasS,
    _Float16* __restrict__ q16, _Float16* __restrict__ q16T,
    float* __restrict__ Ct)
{
  __shared__ float part[4 * 16 * 68];     // 17408 B, stride 68 (conflict-free)
  __shared__ _Float16 qs[16 * 68];        // f16 summed q for transposed store
  __shared__ float sumsq[16];

  const int tid  = threadIdx.x;
  const int w    = tid >> 6, lane = tid & 63;
  const int n    = lane & 15, quad = lane >> 4;
  const int r0   = blockIdx.x * 16;       // global row base (= b*2048 + t)
  const int k0   = w * 192;

  const float*    xp = x   + (size_t)(r0 + n) * 768 + k0 + quad * 8;
  const _Float16* wp = WqT + (size_t)n * 768 + k0 + quad * 8;

  floatx4 acc[4];
  #pragma unroll
  for (int s = 0; s < 4; ++s) acc[s] = (floatx4){0.f, 0.f, 0.f, 0.f};

  #pragma unroll 2
  for (int ks = 0; ks < 192; ks += 32) {
    float4 x0 = *(const float4*)(xp + ks);
    float4 x1 = *(const float4*)(xp + ks + 4);
    half8 b0 = *(const half8*)(wp + ks);
    half8 b1 = *(const half8*)(wp + 16 * 768 + ks);
    half8 b2 = *(const half8*)(wp + 32 * 768 + ks);
    half8 b3 = *(const half8*)(wp + 48 * 768 + ks);
    half8 a;
    a[0] = (_Float16)x0.x; a[1] = (_Float16)x0.y;
    a[2] = (_Float16)x0.z; a[3] = (_Float16)x0.w;
    a[4] = (_Float16)x1.x; a[5] = (_Float16)x1.y;
    a[6] = (_Float16)x1.z; a[7] = (_Float16)x1.w;
    acc[0] = __builtin_amdgcn_mfma_f32_16x16x32_f16(a, b0, acc[0], 0, 0, 0);
    acc[1] = __builtin_amdgcn_mfma_f32_16x16x32_f16(a, b1, acc[1], 0, 0, 0);
    acc[2] = __builtin_amdgcn_mfma_f32_16x16x32_f16(a, b2, acc[2], 0, 0, 0);
    acc[3] = __builtin_amdgcn_mfma_f32_16x16x32_f16(a, b3, acc[3], 0, 0, 0);
  }

  // partial C tiles -> LDS   (C layout: col = n -> h, row = 4*quad + r)
  #pragma unroll
  for (int sub = 0; sub < 4; ++sub)
    #pragma unroll
    for (int r = 0; r < 4; ++r)
      part[w * 1088 + (4 * quad + r) * 68 + sub * 16 + n] = acc[sub][r];
  __syncthreads();

  const float b0v = biasS[2047];
  #pragma unroll
  for (int k = 0; k < 4; ++k) {
    int e = tid + k * 256;
    int row = e >> 6, h = e & 63;       // row is wave-uniform
    float s = part[row * 68 + h] + part[1088 + row * 68 + h] +
              part[2176 + row * 68 + h] + part[3264 + row * 68 + h];
    q16[(size_t)(r0 + row) * 64 + h] = (_Float16)s;
    qs[row * 68 + h] = (_Float16)s;
    float ss = s * s;
    #pragma unroll
    for (int off = 1; off < 64; off <<= 1) ss += __shfl_xor(ss, off);
    if (lane == 0) sumsq[row] = ss;
  }
  __syncthreads();

  if (tid < 16)
    Ct[r0 + tid] = sumsq[tid] * 0.18033688f + b0v + 8.0f;

  // transposed q16T[b][h][t]: thread -> (h = tid/4, 4 consecutive rows)
  {
    const int h = tid >> 2, rq = (tid & 3) * 4;
    half4 hv;
    hv[0] = qs[(rq + 0) * 68 + h]; hv[1] = qs[(rq + 1) * 68 + h];
    hv[2] = qs[(rq + 2) * 68 + h]; hv[3] = qs[(rq + 3) * 68 + h];
    const int bb = r0 >> 11, tt = r0 & 2047;
    *(half4*)(q16T + (size_t)(bb * 64 + h) * T_SEQ + tt + rq) = hv;
  }
}

// ---------------------------------------------------------------------------
// Kernel 2: attention, fixed per-row-offset softmax (no max tracking).
// 1024 blocks x 512 threads; block = (b, 16-row Q-tile); 8 waves K-split;
// additive LDS combine; denominator via ones-column MFMA.
// ---------------------------------------------------------------------------
__global__ __launch_bounds__(512, 8) void attn_kernel(
    const _Float16* __restrict__ q16, const _Float16* __restrict__ q16T,
    const float* __restrict__ biasS, const float* __restrict__ Ct,
    float* __restrict__ out)
{
  __shared__ __align__(16) _Float16 Pbuf[8 * 16 * 72];  // 18432 B
  __shared__ float Obuf[16 * 65];                       // 4160 B
  __shared__ float Lbuf[16];
  __shared__ float biasL[2080];                         // 8320 B

  // CU-balanced map: 4 slots with complementary q-tile weights
  const int bi   = blockIdx.x;
  const int u    = (bi & 255) >> 3, slot = bi >> 8;
  const int qi   = (slot == 0) ? 127 - u : (slot == 1) ? 64 + u
                 : (slot == 2) ? 63 - u  : u;
  const int b    = bi & 7;
  const int t0   = qi * 16;
  const int nkt  = (t0 >> 6) + 1;

  const int tid  = threadIdx.x;
  const int w    = tid >> 6;
  const int lane = tid & 63;
  const int n    = lane & 15, quad = lane >> 4;

  for (int i = tid; i < 16 * 65; i += 512) Obuf[i] = 0.f;
  if (tid < 16) Lbuf[tid] = 0.f;
  {
    const int lo = 2032 - t0, cnt = t0 + 31;
    for (int i = tid; i < cnt; i += 512) biasL[i] = biasS[lo + i];
  }

  half8 aq0, aq1;
  {
    const _Float16* qrow = q16 + (size_t)(b * T_SEQ + t0 + n) * 64 + quad * 8;
    aq0 = *(const half8*)qrow;
    aq1 = *(const half8*)(qrow + 32);
  }
  float ctv[4];
  #pragma unroll
  for (int r = 0; r < 4; ++r)
    ctv[r] = Ct[b * T_SEQ + t0 + 4 * quad + r];

  floatx4 O[4];
  #pragma unroll
  for (int s = 0; s < 4; ++s) O[s] = (floatx4){0.f, 0.f, 0.f, 0.f};
  floatx4 den = (floatx4){0.f, 0.f, 0.f, 0.f};
  const half8 ones = {(_Float16)1, (_Float16)1, (_Float16)1, (_Float16)1,
                      (_Float16)1, (_Float16)1, (_Float16)1, (_Float16)1};

  _Float16* Pw = Pbuf + w * (16 * 72);
  const float ksc = 0.125f * 1.44269504f;

  __syncthreads();

  for (int kt = w; kt < nkt; kt += 8) {
    const int s0 = kt * 64;

    #pragma unroll
    for (int sub = 0; sub < 4; ++sub) {
      const int smin = s0 + sub * 16;
      if (smin > t0 + 15) {               // fully masked: store zeros
        #pragma unroll
        for (int r = 0; r < 4; ++r)
          Pw[(4 * quad + r) * 72 + sub * 16 + n] = (_Float16)0.f;
        continue;
      }
      const _Float16* kp = q16 + (size_t)(b * T_SEQ + smin + n) * 64 + quad * 8;
      half8 bk0 = *(const half8*)kp;
      half8 bk1 = *(const half8*)(kp + 32);
      floatx4 sc = (floatx4){0.f, 0.f, 0.f, 0.f};
      sc = __builtin_amdgcn_mfma_f32_16x16x32_f16(aq0, bk0, sc, 0, 0, 0);
      sc = __builtin_amdgcn_mfma_f32_16x16x32_f16(aq1, bk1, sc, 0, 0, 0);
      const int  sIdx = smin + n;
      const bool part = (smin + 15 > t0);
      #pragma unroll
      for (int r = 0; r < 4; ++r) {
        float bv  = biasL[15 + sIdx - 4 * quad - r];
        float arg = fmaf(sc[r], ksc, bv) - ctv[r];
        float p   = exp2f(arg);
        if (part && sIdx > t0 + 4 * quad + r) p = 0.f;
        Pw[(4 * quad + r) * 72 + sub * 16 + n] = (_Float16)p;
      }
    }

    // O += P V ; den += P * 1   (A = P from per-wave LDS)
    #pragma unroll
    for (int ch = 0; ch < 2; ++ch) {
      half8 pf = *(const half8*)(Pw + n * 72 + ch * 32 + quad * 8);
      den = __builtin_amdgcn_mfma_f32_16x16x32_f16(pf, ones, den, 0, 0, 0);
      #pragma unroll
      for (int sh = 0; sh < 4; ++sh) {
        half8 vf = *(const half8*)(q16T +
            (size_t)(b * 64 + sh * 16 + n) * T_SEQ + s0 + ch * 32 + quad * 8);
        O[sh] = __builtin_amdgcn_mfma_f32_16x16x32_f16(pf, vf, O[sh], 0, 0, 0);
      }
    }
  }

  // additive cross-wave combine
  #pragma unroll
  for (int sub = 0; sub < 4; ++sub)
    #pragma unroll
    for (int r = 0; r < 4; ++r)
      atomicAdd(&Obuf[(4 * quad + r) * 65 + sub * 16 + n], O[sub][r]);
  if (n == 0) {
    #pragma unroll
    for (int r = 0; r < 4; ++r)
      atomicAdd(&Lbuf[4 * quad + r], den[r]);
  }
  __syncthreads();

  for (int e = tid; e < 1024; e += 512) {
    const int row = e >> 6, h = e & 63;
    out[(size_t)(b * T_SEQ + t0 + row) * 64 + h] =
        Obuf[row * 65 + h] / Lbuf[row];
  }
}

// ---------------------------------------------------------------------------
extern "C" void kernel_launch(void* const* d_in, const int* in_sizes, int n_in,
                              void* d_out, int out_size, void* d_ws, size_t ws_size,
                              hipStream_t stream) {
  const float* x   = (const float*)d_in[0];
  const float* Wq  = (const float*)d_in[1];
  const float* rel = (const float*)d_in[2];
  float* out = (float*)d_out;

  _Float16* q16   = (_Float16*)d_ws;                    // [8][2048][64]
  _Float16* q16T  = q16  + (size_t)NB * T_SEQ * 64;     // [8][64][2048]
  _Float16* WqT   = q16T + (size_t)NB * T_SEQ * 64;     // [64][768]
  float*    biasS = (float*)(WqT + 64 * 768);           // [4095] (+pad)
  float*    Ct    = biasS + 4096;                       // [16384]

  prep_kernel <<<65,   256, 0, stream>>>(Wq, rel, WqT, biasS);
  qproj_kernel<<<1024, 256, 0, stream>>>(x, WqT, biasS, q16, q16T, Ct);
  attn_kernel <<<1024, 512, 0, stream>>>(q16, q16T, biasS, Ct, out);
}

// Round 4
// 180.564 us; speedup vs baseline: 1.0193x; 1.0193x over previous
//
#include <hip/hip_runtime.h>
#include <hip/hip_fp16.h>

typedef _Float16 half8 __attribute__((ext_vector_type(8)));
typedef _Float16 half4 __attribute__((ext_vector_type(4)));
typedef float floatx4 __attribute__((ext_vector_type(4)));

#define T_SEQ 2048
#define NB    8

// ---------------------------------------------------------------------------
// Kernel 0: prep — WqT f16 [64][768] and bias*log2e table [4095]
// ---------------------------------------------------------------------------
__global__ __launch_bounds__(256) void prep_kernel(
    const float* __restrict__ Wq, const float* __restrict__ rel,
    _Float16* __restrict__ WqT, float* __restrict__ biasS)
{
  const int bid = blockIdx.x, tid = threadIdx.x;
  if (bid < 64) {
    for (int k = tid; k < 768; k += 256)
      WqT[bid * 768 + k] = (_Float16)Wq[k * 64 + bid];
  } else {
    for (int i = tid; i < 4095; i += 256)
      biasS[i] = rel[i] * 1.44269504f;
  }
}

// ---------------------------------------------------------------------------
// Kernel 1: q = x @ Wq. 1024 blocks x 256 threads; 16 rows/block;
// K split across 4 waves (192 each). All 12 x-loads issued up front
// (12 outstanding HBM loads/wave -> ~192/CU: latency covered).
// Emits per-row softmax offset Ct = (|q|^2/8)*log2e + bias0 + 8.
// ---------------------------------------------------------------------------
__global__ __launch_bounds__(256, 4) void qproj_kernel(
    const float* __restrict__ x, const _Float16* __restrict__ WqT,
    const float* __restrict__ biasS,
    _Float16* __restrict__ q16, _Float16* __restrict__ q16T,
    float* __restrict__ Ct)
{
  __shared__ float part[4 * 16 * 68];
  __shared__ _Float16 qs[16 * 68];
  __shared__ float sumsq[16];

  const int tid  = threadIdx.x;
  const int w    = tid >> 6, lane = tid & 63;
  const int n    = lane & 15, quad = lane >> 4;
  const int r0   = blockIdx.x * 16;
  const int k0   = w * 192;

  const float*    xp = x   + (size_t)(r0 + n) * 768 + k0 + quad * 8;
  const _Float16* wp = WqT + (size_t)n * 768 + k0 + quad * 8;

  // burst-issue all x loads (48 VGPRs, 12 outstanding HBM loads)
  float4 xr[12];
  #pragma unroll
  for (int i = 0; i < 6; ++i) {
    xr[2 * i]     = *(const float4*)(xp + 32 * i);
    xr[2 * i + 1] = *(const float4*)(xp + 32 * i + 4);
  }

  floatx4 acc[4];
  #pragma unroll
  for (int s = 0; s < 4; ++s) acc[s] = (floatx4){0.f, 0.f, 0.f, 0.f};

  #pragma unroll
  for (int i = 0; i < 6; ++i) {
    const int ks = 32 * i;
    half8 b0 = *(const half8*)(wp + ks);
    half8 b1 = *(const half8*)(wp + 16 * 768 + ks);
    half8 b2 = *(const half8*)(wp + 32 * 768 + ks);
    half8 b3 = *(const half8*)(wp + 48 * 768 + ks);
    half8 a;
    a[0] = (_Float16)xr[2 * i].x; a[1] = (_Float16)xr[2 * i].y;
    a[2] = (_Float16)xr[2 * i].z; a[3] = (_Float16)xr[2 * i].w;
    a[4] = (_Float16)xr[2 * i + 1].x; a[5] = (_Float16)xr[2 * i + 1].y;
    a[6] = (_Float16)xr[2 * i + 1].z; a[7] = (_Float16)xr[2 * i + 1].w;
    acc[0] = __builtin_amdgcn_mfma_f32_16x16x32_f16(a, b0, acc[0], 0, 0, 0);
    acc[1] = __builtin_amdgcn_mfma_f32_16x16x32_f16(a, b1, acc[1], 0, 0, 0);
    acc[2] = __builtin_amdgcn_mfma_f32_16x16x32_f16(a, b2, acc[2], 0, 0, 0);
    acc[3] = __builtin_amdgcn_mfma_f32_16x16x32_f16(a, b3, acc[3], 0, 0, 0);
  }

  // partial C tiles -> LDS  (C layout: col = n -> h, row = 4*quad + r)
  #pragma unroll
  for (int sub = 0; sub < 4; ++sub)
    #pragma unroll
    for (int r = 0; r < 4; ++r)
      part[w * 1088 + (4 * quad + r) * 68 + sub * 16 + n] = acc[sub][r];
  __syncthreads();

  const float b0v = biasS[2047];
  #pragma unroll
  for (int k = 0; k < 4; ++k) {
    int e = tid + k * 256;
    int row = e >> 6, h = e & 63;
    float s = part[row * 68 + h] + part[1088 + row * 68 + h] +
              part[2176 + row * 68 + h] + part[3264 + row * 68 + h];
    q16[(size_t)(r0 + row) * 64 + h] = (_Float16)s;
    qs[row * 68 + h] = (_Float16)s;
    float ss = s * s;
    #pragma unroll
    for (int off = 1; off < 64; off <<= 1) ss += __shfl_xor(ss, off);
    if (lane == 0) sumsq[row] = ss;
  }
  __syncthreads();

  if (tid < 16)
    Ct[r0 + tid] = sumsq[tid] * 0.18033688f + b0v + 8.0f;

  {
    const int h = tid >> 2, rq = (tid & 3) * 4;
    half4 hv;
    hv[0] = qs[(rq + 0) * 68 + h]; hv[1] = qs[(rq + 1) * 68 + h];
    hv[2] = qs[(rq + 2) * 68 + h]; hv[3] = qs[(rq + 3) * 68 + h];
    const int bb = r0 >> 11, tt = r0 & 2047;
    *(half4*)(q16T + (size_t)(bb * 64 + h) * T_SEQ + tt + rq) = hv;
  }
}

// ---------------------------------------------------------------------------
// Kernel 2: attention, fixed per-row-offset softmax. 1024 blocks x 512 thr;
// block = (b, 16-row Q-tile); 8 waves K-split; V fragments prefetched before
// the S/P computation (32 VGPRs in flight); branch-free full tiles + one
// masked diagonal tile; additive LDS combine.
// ---------------------------------------------------------------------------
__global__ __launch_bounds__(512, 4) void attn_kernel(
    const _Float16* __restrict__ q16, const _Float16* __restrict__ q16T,
    const float* __restrict__ biasS, const float* __restrict__ Ct,
    float* __restrict__ out)
{
  __shared__ __align__(16) _Float16 Pbuf[8 * 16 * 72];  // 18432 B
  __shared__ float Obuf[16 * 65];                       // 4160 B
  __shared__ float Lbuf[16];
  __shared__ float biasL[2080];                         // 8320 B

  // fine-grained heavy/light pairing: balanced under any dispatch chunking
  const int bi = blockIdx.x;
  const int u  = bi >> 3;
  const int qi = (u & 1) ? (u >> 1) : (127 - (u >> 1));
  const int b  = bi & 7;
  const int t0 = qi * 16;
  const int kfull = t0 >> 6;              // k-tiles [0,kfull) are unmasked

  const int tid  = threadIdx.x;
  const int w    = tid >> 6;
  const int lane = tid & 63;
  const int n    = lane & 15, quad = lane >> 4;

  for (int i = tid; i < 16 * 65; i += 512) Obuf[i] = 0.f;
  if (tid < 16) Lbuf[tid] = 0.f;
  {
    const int lo = 2032 - t0, cnt = t0 + 31;
    for (int i = tid; i < cnt; i += 512) biasL[i] = biasS[lo + i];
  }

  half8 aq0, aq1;
  {
    const _Float16* qrow = q16 + (size_t)(b * T_SEQ + t0 + n) * 64 + quad * 8;
    aq0 = *(const half8*)qrow;
    aq1 = *(const half8*)(qrow + 32);
  }
  float ctv[4];
  #pragma unroll
  for (int r = 0; r < 4; ++r)
    ctv[r] = Ct[b * T_SEQ + t0 + 4 * quad + r];

  floatx4 O[4];
  #pragma unroll
  for (int s = 0; s < 4; ++s) O[s] = (floatx4){0.f, 0.f, 0.f, 0.f};
  floatx4 den = (floatx4){0.f, 0.f, 0.f, 0.f};
  const half8 ones = {(_Float16)1, (_Float16)1, (_Float16)1, (_Float16)1,
                      (_Float16)1, (_Float16)1, (_Float16)1, (_Float16)1};

  _Float16* Pw = Pbuf + w * (16 * 72);
  const float ksc = 0.125f * 1.44269504f;
  const _Float16* vbase = q16T + (size_t)(b * 64 + n) * T_SEQ + quad * 8;

  __syncthreads();

  // ---- full (unmasked) k-tiles ----
  for (int kt = w; kt < kfull; kt += 8) {
    const int s0 = kt * 64;

    // prefetch all 8 V fragments (independent of P -> overlaps S/softmax)
    half8 vf[8];
    #pragma unroll
    for (int sh = 0; sh < 4; ++sh) {
      vf[sh]     = *(const half8*)(vbase + (size_t)sh * 16 * T_SEQ + s0);
      vf[4 + sh] = *(const half8*)(vbase + (size_t)sh * 16 * T_SEQ + s0 + 32);
    }

    #pragma unroll
    for (int sub = 0; sub < 4; ++sub) {
      const int smin = s0 + sub * 16;
      const _Float16* kp = q16 + (size_t)(b * T_SEQ + smin + n) * 64 + quad * 8;
      half8 bk0 = *(const half8*)kp;
      half8 bk1 = *(const half8*)(kp + 32);
      floatx4 sc = (floatx4){0.f, 0.f, 0.f, 0.f};
      sc = __builtin_amdgcn_mfma_f32_16x16x32_f16(aq0, bk0, sc, 0, 0, 0);
      sc = __builtin_amdgcn_mfma_f32_16x16x32_f16(aq1, bk1, sc, 0, 0, 0);
      #pragma unroll
      for (int r = 0; r < 4; ++r) {
        float bv = biasL[15 + smin + n - 4 * quad - r];
        float p  = exp2f(fmaf(sc[r], ksc, bv) - ctv[r]);
        Pw[(4 * quad + r) * 72 + sub * 16 + n] = (_Float16)p;
      }
    }

    #pragma unroll
    for (int ch = 0; ch < 2; ++ch) {
      half8 pf = *(const half8*)(Pw + n * 72 + ch * 32 + quad * 8);
      den = __builtin_amdgcn_mfma_f32_16x16x32_f16(pf, ones, den, 0, 0, 0);
      #pragma unroll
      for (int sh = 0; sh < 4; ++sh)
        O[sh] = __builtin_amdgcn_mfma_f32_16x16x32_f16(pf, vf[ch * 4 + sh],
                                                       O[sh], 0, 0, 0);
    }
  }

  // ---- diagonal (masked) k-tile: kt == kfull, owned by wave kfull&7 ----
  if ((kfull & 7) == w) {
    const int s0 = kfull * 64;
    const int j  = (t0 - s0) >> 4;        // diagonal sub-tile index

    half8 vf[8];
    #pragma unroll
    for (int sh = 0; sh < 4; ++sh) {
      vf[sh]     = *(const half8*)(vbase + (size_t)sh * 16 * T_SEQ + s0);
      vf[4 + sh] = *(const half8*)(vbase + (size_t)sh * 16 * T_SEQ + s0 + 32);
    }

    #pragma unroll
    for (int sub = 0; sub < 4; ++sub) {
      if (sub > j) {
        #pragma unroll
        for (int r = 0; r < 4; ++r)
          Pw[(4 * quad + r) * 72 + sub * 16 + n] = (_Float16)0.f;
        continue;
      }
      const int smin = s0 + sub * 16;
      const _Float16* kp = q16 + (size_t)(b * T_SEQ + smin + n) * 64 + quad * 8;
      half8 bk0 = *(const half8*)kp;
      half8 bk1 = *(const half8*)(kp + 32);
      floatx4 sc = (floatx4){0.f, 0.f, 0.f, 0.f};
      sc = __builtin_amdgcn_mfma_f32_16x16x32_f16(aq0, bk0, sc, 0, 0, 0);
      sc = __builtin_amdgcn_mfma_f32_16x16x32_f16(aq1, bk1, sc, 0, 0, 0);
      #pragma unroll
      for (int r = 0; r < 4; ++r) {
        float bv = biasL[15 + smin + n - 4 * quad - r];
        float p  = exp2f(fmaf(sc[r], ksc, bv) - ctv[r]);
        if (sub == j && n > 4 * quad + r) p = 0.f;   // causal mask on diagonal
        Pw[(4 * quad + r) * 72 + sub * 16 + n] = (_Float16)p;
      }
    }

    #pragma unroll
    for (int ch = 0; ch < 2; ++ch) {
      half8 pf = *(const half8*)(Pw + n * 72 + ch * 32 + quad * 8);
      den = __builtin_amdgcn_mfma_f32_16x16x32_f16(pf, ones, den, 0, 0, 0);
      #pragma unroll
      for (int sh = 0; sh < 4; ++sh)
        O[sh] = __builtin_amdgcn_mfma_f32_16x16x32_f16(pf, vf[ch * 4 + sh],
                                                       O[sh], 0, 0, 0);
    }
  }

  // additive cross-wave combine
  #pragma unroll
  for (int sub = 0; sub < 4; ++sub)
    #pragma unroll
    for (int r = 0; r < 4; ++r)
      atomicAdd(&Obuf[(4 * quad + r) * 65 + sub * 16 + n], O[sub][r]);
  if (n == 0) {
    #pragma unroll
    for (int r = 0; r < 4; ++r)
      atomicAdd(&Lbuf[4 * quad + r], den[r]);
  }
  __syncthreads();

  for (int e = tid; e < 1024; e += 512) {
    const int row = e >> 6, h = e & 63;
    out[(size_t)(b * T_SEQ + t0 + row) * 64 + h] =
        Obuf[row * 65 + h] / Lbuf[row];
  }
}

// ---------------------------------------------------------------------------
extern "C" void kernel_launch(void* const* d_in, const int* in_sizes, int n_in,
                              void* d_out, int out_size, void* d_ws, size_t ws_size,
                              hipStream_t stream) {
  const float* x   = (const float*)d_in[0];
  const float* Wq  = (const float*)d_in[1];
  const float* rel = (const float*)d_in[2];
  float* out = (float*)d_out;

  _Float16* q16   = (_Float16*)d_ws;                    // [8][2048][64]
  _Float16* q16T  = q16  + (size_t)NB * T_SEQ * 64;     // [8][64][2048]
  _Float16* WqT   = q16T + (size_t)NB * T_SEQ * 64;     // [64][768]
  float*    biasS = (float*)(WqT + 64 * 768);           // [4095] (+pad)
  float*    Ct    = biasS + 4096;                       // [16384]

  prep_kernel <<<65,   256, 0, stream>>>(Wq, rel, WqT, biasS);
  qproj_kernel<<<1024, 256, 0, stream>>>(x, WqT, biasS, q16, q16T, Ct);
  attn_kernel <<<1024, 512, 0, stream>>>(q16, q16T, biasS, Ct, out);
}

// Round 5
// 151.616 us; speedup vs baseline: 1.2139x; 1.1909x over previous
//
#include <hip/hip_runtime.h>
#include <hip/hip_fp16.h>

typedef _Float16 half8 __attribute__((ext_vector_type(8)));
typedef _Float16 half4 __attribute__((ext_vector_type(4)));
typedef float floatx4 __attribute__((ext_vector_type(4)));

#define T_SEQ 2048
#define NB    8

#define GLOBAL_AS __attribute__((address_space(1)))
#define LDS_AS    __attribute__((address_space(3)))

// ---------------------------------------------------------------------------
// Kernel 0: prep — WqT f16 [64][768] and bias*log2e table [4095]
// ---------------------------------------------------------------------------
__global__ __launch_bounds__(256) void prep_kernel(
    const float* __restrict__ Wq, const float* __restrict__ rel,
    _Float16* __restrict__ WqT, float* __restrict__ biasS)
{
  const int bid = blockIdx.x, tid = threadIdx.x;
  if (bid < 64) {
    for (int k = tid; k < 768; k += 256)
      WqT[bid * 768 + k] = (_Float16)Wq[k * 64 + bid];
  } else {
    for (int i = tid; i < 4095; i += 256)
      biasS[i] = rel[i] * 1.44269504f;
  }
}

// ---------------------------------------------------------------------------
// Kernel 1: q = x @ Wq, m97-style: async global_load_lds staging of 16
// contiguous x rows (48 KB) + B in registers, MFMA from LDS.
// 1024 blocks x 256 threads (4 waves, K-split 192 each).
// Emits per-row softmax offset Ct = (|q|^2/8)*log2e + bias0 + 8.
// ---------------------------------------------------------------------------
__global__ __launch_bounds__(256, 3) void qproj_kernel(
    const float* __restrict__ x, const _Float16* __restrict__ WqT,
    const float* __restrict__ biasS,
    _Float16* __restrict__ q16, _Float16* __restrict__ q16T,
    float* __restrict__ Ct)
{
  __shared__ __align__(16) float xbuf[16 * 772];   // 49408 B (row pad: 2-way ok)
  __shared__ float sumsq[16];
  // aliases (used only after xbuf is dead):
  float*    part = xbuf;                           // [4][16][68] f32
  _Float16* qs   = (_Float16*)(xbuf + 4 * 16 * 68);// [16][68] f16

  const int tid  = threadIdx.x;
  const int w    = tid >> 6, lane = tid & 63;
  const int n    = lane & 15, quad = lane >> 4;
  const int r0   = blockIdx.x * 16;
  const int k0   = w * 192;

  // ---- async stage: wave w stages rows 4w..4w+3, 3 chunks of 1 KB each ----
  {
    const int row0 = 4 * w;
    #pragma unroll
    for (int r = 0; r < 4; ++r) {
      #pragma unroll
      for (int c = 0; c < 3; ++c) {
        const float* gp = x + (size_t)(r0 + row0 + r) * 768 + c * 256 + lane * 4;
        float* lp = xbuf + (row0 + r) * 772 + c * 256 + lane * 4;
        __builtin_amdgcn_global_load_lds((const GLOBAL_AS void*)gp,
                                         (LDS_AS void*)lp, 16, 0, 0);
      }
    }
  }

  // ---- burst-load all B fragments (WqT, L2/L3) during the staging drain ----
  const _Float16* wp = WqT + (size_t)n * 768 + k0 + quad * 8;
  half8 Breg[6][4];
  #pragma unroll
  for (int i = 0; i < 6; ++i)
    #pragma unroll
    for (int t = 0; t < 4; ++t)
      Breg[i][t] = *(const half8*)(wp + 32 * i + t * 16 * 768);

  __builtin_amdgcn_s_waitcnt(0x0f70);   // vmcnt(0)
  __syncthreads();

  // ---- MFMA from LDS ----
  floatx4 acc[4];
  #pragma unroll
  for (int s = 0; s < 4; ++s) acc[s] = (floatx4){0.f, 0.f, 0.f, 0.f};

  #pragma unroll
  for (int i = 0; i < 6; ++i) {
    const float* ap = xbuf + n * 772 + k0 + 32 * i + quad * 8;
    float4 x0 = *(const float4*)ap;
    float4 x1 = *(const float4*)(ap + 4);
    half8 a;
    a[0] = (_Float16)x0.x; a[1] = (_Float16)x0.y;
    a[2] = (_Float16)x0.z; a[3] = (_Float16)x0.w;
    a[4] = (_Float16)x1.x; a[5] = (_Float16)x1.y;
    a[6] = (_Float16)x1.z; a[7] = (_Float16)x1.w;
    acc[0] = __builtin_amdgcn_mfma_f32_16x16x32_f16(a, Breg[i][0], acc[0], 0, 0, 0);
    acc[1] = __builtin_amdgcn_mfma_f32_16x16x32_f16(a, Breg[i][1], acc[1], 0, 0, 0);
    acc[2] = __builtin_amdgcn_mfma_f32_16x16x32_f16(a, Breg[i][2], acc[2], 0, 0, 0);
    acc[3] = __builtin_amdgcn_mfma_f32_16x16x32_f16(a, Breg[i][3], acc[3], 0, 0, 0);
  }

  __syncthreads();                      // xbuf dead -> reuse as part/qs

  #pragma unroll
  for (int sub = 0; sub < 4; ++sub)
    #pragma unroll
    for (int r = 0; r < 4; ++r)
      part[w * 1088 + (4 * quad + r) * 68 + sub * 16 + n] = acc[sub][r];
  __syncthreads();

  const float b0v = biasS[2047];
  #pragma unroll
  for (int k = 0; k < 4; ++k) {
    int e = tid + k * 256;
    int row = e >> 6, h = e & 63;
    float s = part[row * 68 + h] + part[1088 + row * 68 + h] +
              part[2176 + row * 68 + h] + part[3264 + row * 68 + h];
    q16[(size_t)(r0 + row) * 64 + h] = (_Float16)s;
    qs[row * 68 + h] = (_Float16)s;
    float ss = s * s;
    #pragma unroll
    for (int off = 1; off < 64; off <<= 1) ss += __shfl_xor(ss, off);
    if (lane == 0) sumsq[row] = ss;
  }
  __syncthreads();

  if (tid < 16)
    Ct[r0 + tid] = sumsq[tid] * 0.18033688f + b0v + 8.0f;

  {
    const int h = tid >> 2, rq = (tid & 3) * 4;
    half4 hv;
    hv[0] = qs[(rq + 0) * 68 + h]; hv[1] = qs[(rq + 1) * 68 + h];
    hv[2] = qs[(rq + 2) * 68 + h]; hv[3] = qs[(rq + 3) * 68 + h];
    const int bb = r0 >> 11, tt = r0 & 2047;
    *(half4*)(q16T + (size_t)(bb * 64 + h) * T_SEQ + tt + rq) = hv;
  }
}

// ---------------------------------------------------------------------------
// Kernel 2: attention, fixed-offset softmax. 1024 blocks x 128 thr (2 waves);
// block = (b, 16-row Q-tile); k-split 2 across waves; full K+V register
// double-buffer (next tile issued before computing current); non-atomic
// 2-way LDS combine. Whole grid co-resident (4 blocks/CU).
// ---------------------------------------------------------------------------
__global__ __launch_bounds__(128, 2) void attn_kernel(
    const _Float16* __restrict__ q16, const _Float16* __restrict__ q16T,
    const float* __restrict__ biasS, const float* __restrict__ Ct,
    float* __restrict__ out)
{
  __shared__ __align__(16) _Float16 Pbuf[2 * 16 * 72];  // 4608 B
  __shared__ float Obuf[2 * 16 * 65];                   // 8320 B
  __shared__ float Lbuf[2 * 16];
  __shared__ float biasL[2080];                         // 8320 B

  const int bi = blockIdx.x;
  const int u  = bi >> 3;
  const int qi = (u & 1) ? (u >> 1) : (127 - (u >> 1));
  const int b  = bi & 7;
  const int t0 = qi * 16;
  const int kfull = t0 >> 6;            // tiles [0,kfull) unmasked; kfull = diag

  const int tid  = threadIdx.x;
  const int w    = tid >> 6;
  const int lane = tid & 63;
  const int n    = lane & 15, quad = lane >> 4;

  {
    const int lo = 2032 - t0, cnt = t0 + 31;
    for (int i = tid; i < cnt; i += 128) biasL[i] = biasS[lo + i];
  }

  half8 aq0, aq1;
  {
    const _Float16* qrow = q16 + (size_t)(b * T_SEQ + t0 + n) * 64 + quad * 8;
    aq0 = *(const half8*)qrow;
    aq1 = *(const half8*)(qrow + 32);
  }
  float ctv[4];
  #pragma unroll
  for (int r = 0; r < 4; ++r)
    ctv[r] = Ct[b * T_SEQ + t0 + 4 * quad + r];

  floatx4 O[4];
  #pragma unroll
  for (int s = 0; s < 4; ++s) O[s] = (floatx4){0.f, 0.f, 0.f, 0.f};
  floatx4 den = (floatx4){0.f, 0.f, 0.f, 0.f};
  const half8 ones = {(_Float16)1, (_Float16)1, (_Float16)1, (_Float16)1,
                      (_Float16)1, (_Float16)1, (_Float16)1, (_Float16)1};

  _Float16* Pw = Pbuf + w * (16 * 72);
  const float ksc = 0.125f * 1.44269504f;
  const _Float16* vbase = q16T + (size_t)(b * 64 + n) * T_SEQ + quad * 8;

  __syncthreads();

  half8 cK[8], cV[8], nK[8], nV[8];

  #define LOAD_KV(S0, K, V)                                                   \
    {                                                                         \
      _Pragma("unroll")                                                       \
      for (int sub = 0; sub < 4; ++sub) {                                     \
        const _Float16* kp =                                                  \
            q16 + (size_t)(b * T_SEQ + (S0) + sub * 16 + n) * 64 + quad * 8;  \
        K[2 * sub]     = *(const half8*)kp;                                   \
        K[2 * sub + 1] = *(const half8*)(kp + 32);                            \
      }                                                                       \
      _Pragma("unroll")                                                       \
      for (int sh = 0; sh < 4; ++sh) {                                        \
        V[sh]     = *(const half8*)(vbase + (size_t)(sh * 16) * T_SEQ + (S0));\
        V[4 + sh] = *(const half8*)(vbase + (size_t)(sh * 16) * T_SEQ + (S0) + 32); \
      }                                                                       \
    }

  int kt = w;
  if (kt <= kfull) LOAD_KV(kt * 64, cK, cV);

  for (; kt <= kfull; kt += 2) {
    const int ktn = kt + 2;
    if (ktn <= kfull) LOAD_KV(ktn * 64, nK, nV);

    const int  s0 = kt * 64;
    const bool dg = (kt == kfull);
    const int  j  = (t0 - s0) >> 4;     // valid when dg

    #pragma unroll
    for (int sub = 0; sub < 4; ++sub) {
      if (dg && sub > j) {
        #pragma unroll
        for (int r = 0; r < 4; ++r)
          Pw[(4 * quad + r) * 72 + sub * 16 + n] = (_Float16)0.f;
        continue;
      }
      floatx4 sc = (floatx4){0.f, 0.f, 0.f, 0.f};
      sc = __builtin_amdgcn_mfma_f32_16x16x32_f16(aq0, cK[2 * sub], sc, 0, 0, 0);
      sc = __builtin_amdgcn_mfma_f32_16x16x32_f16(aq1, cK[2 * sub + 1], sc, 0, 0, 0);
      const int smin = s0 + sub * 16;
      #pragma unroll
      for (int r = 0; r < 4; ++r) {
        float bv = biasL[15 + smin + n - 4 * quad - r];
        float p  = exp2f(fmaf(sc[r], ksc, bv) - ctv[r]);
        if (dg && sub == j && n > 4 * quad + r) p = 0.f;  // causal diag mask
        Pw[(4 * quad + r) * 72 + sub * 16 + n] = (_Float16)p;
      }
    }

    #pragma unroll
    for (int ch = 0; ch < 2; ++ch) {
      half8 pf = *(const half8*)(Pw + n * 72 + ch * 32 + quad * 8);
      den = __builtin_amdgcn_mfma_f32_16x16x32_f16(pf, ones, den, 0, 0, 0);
      #pragma unroll
      for (int sh = 0; sh < 4; ++sh)
        O[sh] = __builtin_amdgcn_mfma_f32_16x16x32_f16(pf, cV[ch * 4 + sh],
                                                       O[sh], 0, 0, 0);
    }

    #pragma unroll
    for (int i = 0; i < 8; ++i) { cK[i] = nK[i]; cV[i] = nV[i]; }
  }
  #undef LOAD_KV

  // ---- non-atomic 2-way combine ----
  #pragma unroll
  for (int sub = 0; sub < 4; ++sub)
    #pragma unroll
    for (int r = 0; r < 4; ++r)
      Obuf[w * 1040 + (4 * quad + r) * 65 + sub * 16 + n] = O[sub][r];
  if (n == 0) {
    #pragma unroll
    for (int r = 0; r < 4; ++r)
      Lbuf[w * 16 + 4 * quad + r] = den[r];
  }
  __syncthreads();

  for (int e = tid; e < 1024; e += 128) {
    const int row = e >> 6, h = e & 63;
    float num = Obuf[row * 65 + h] + Obuf[1040 + row * 65 + h];
    float d   = Lbuf[row] + Lbuf[16 + row];
    out[(size_t)(b * T_SEQ + t0 + row) * 64 + h] = num / d;
  }
}

// ---------------------------------------------------------------------------
extern "C" void kernel_launch(void* const* d_in, const int* in_sizes, int n_in,
                              void* d_out, int out_size, void* d_ws, size_t ws_size,
                              hipStream_t stream) {
  const float* x   = (const float*)d_in[0];
  const float* Wq  = (const float*)d_in[1];
  const float* rel = (const float*)d_in[2];
  float* out = (float*)d_out;

  _Float16* q16   = (_Float16*)d_ws;                    // [8][2048][64]
  _Float16* q16T  = q16  + (size_t)NB * T_SEQ * 64;     // [8][64][2048]
  _Float16* WqT   = q16T + (size_t)NB * T_SEQ * 64;     // [64][768]
  float*    biasS = (float*)(WqT + 64 * 768);           // [4095] (+pad)
  float*    Ct    = biasS + 4096;                       // [16384]

  prep_kernel <<<65,   256, 0, stream>>>(Wq, rel, WqT, biasS);
  qproj_kernel<<<1024, 256, 0, stream>>>(x, WqT, biasS, q16, q16T, Ct);
  attn_kernel <<<1024, 128, 0, stream>>>(q16, q16T, biasS, Ct, out);
}

// Round 6
// 134.862 us; speedup vs baseline: 1.3647x; 1.1242x over previous
//
#include <hip/hip_runtime.h>
#include <hip/hip_fp16.h>

typedef _Float16 half8 __attribute__((ext_vector_type(8)));
typedef _Float16 half4 __attribute__((ext_vector_type(4)));
typedef float floatx4 __attribute__((ext_vector_type(4)));

#define T_SEQ 2048
#define NB    8

#define GLOBAL_AS __attribute__((address_space(1)))
#define LDS_AS    __attribute__((address_space(3)))

// ---------------------------------------------------------------------------
// Kernel 0: prep — WqT f16 [64][768] and bias*log2e table [4095]
// ---------------------------------------------------------------------------
__global__ __launch_bounds__(256) void prep_kernel(
    const float* __restrict__ Wq, const float* __restrict__ rel,
    _Float16* __restrict__ WqT, float* __restrict__ biasS)
{
  const int bid = blockIdx.x, tid = threadIdx.x;
  if (bid < 64) {
    for (int k = tid; k < 768; k += 256)
      WqT[bid * 768 + k] = (_Float16)Wq[k * 64 + bid];
  } else {
    for (int i = tid; i < 4095; i += 256)
      biasS[i] = rel[i] * 1.44269504f;
  }
}

// ---------------------------------------------------------------------------
// Kernel 1: q = x @ Wq. Persistent: 512 blocks x 256 thr, each block does TWO
// 16-row tiles; B-fragments held in registers across tiles; global_load_lds
// staging; 2 blocks/CU so stage of one overlaps compute of the other.
// Emits per-row softmax offset Ct = (|q|^2/8)*log2e + bias0*log2e + 8.
// ---------------------------------------------------------------------------
__global__ __launch_bounds__(256, 2) void qproj_kernel(
    const float* __restrict__ x, const _Float16* __restrict__ WqT,
    const float* __restrict__ rel,
    _Float16* __restrict__ q16, _Float16* __restrict__ q16T,
    float* __restrict__ Ct)
{
  __shared__ __align__(16) float xbuf[16 * 772];   // 49408 B
  __shared__ float part[2 * 16 * 66];              // 8448 B
  __shared__ float sumsq[16];
  _Float16* qs = (_Float16*)xbuf;                  // alias: used after xbuf dead

  const int tid  = threadIdx.x;
  const int w    = tid >> 6, lane = tid & 63;
  const int n    = lane & 15, quad = lane >> 4;
  const int k0   = w * 192;

  // persistent B fragments (full WqT slice for this wave's k-range)
  const _Float16* wp = WqT + (size_t)n * 768 + k0 + quad * 8;
  half8 Breg[6][4];
  #pragma unroll
  for (int i = 0; i < 6; ++i)
    #pragma unroll
    for (int t = 0; t < 4; ++t)
      Breg[i][t] = *(const half8*)(wp + 32 * i + t * 16 * 768);

  const float b0v = rel[2047] * 1.44269504f;
  float* partw = part + (w & 1) * 1056;            // 1056 = 16*66

  #pragma unroll 1
  for (int it = 0; it < 2; ++it) {
    const int r0 = (blockIdx.x + it * 512) * 16;

    __syncthreads();   // previous iteration's qs readers done -> xbuf free

    // stage 16 rows x 3 KB: wave w stages rows 4w..4w+3, 3 chunks of 1 KB
    #pragma unroll
    for (int r = 0; r < 4; ++r) {
      #pragma unroll
      for (int c = 0; c < 3; ++c) {
        const float* gp = x + (size_t)(r0 + 4 * w + r) * 768 + c * 256 + lane * 4;
        float* lp = xbuf + (4 * w + r) * 772 + c * 256 + lane * 4;
        __builtin_amdgcn_global_load_lds((const GLOBAL_AS void*)gp,
                                         (LDS_AS void*)lp, 16, 0, 0);
      }
    }
    __builtin_amdgcn_s_waitcnt(0x0f70);   // vmcnt(0)
    __syncthreads();

    floatx4 acc[4];
    #pragma unroll
    for (int s = 0; s < 4; ++s) acc[s] = (floatx4){0.f, 0.f, 0.f, 0.f};

    #pragma unroll
    for (int i = 0; i < 6; ++i) {
      const float* ap = xbuf + n * 772 + k0 + 32 * i + quad * 8;
      float4 x0 = *(const float4*)ap;
      float4 x1 = *(const float4*)(ap + 4);
      half8 a;
      a[0] = (_Float16)x0.x; a[1] = (_Float16)x0.y;
      a[2] = (_Float16)x0.z; a[3] = (_Float16)x0.w;
      a[4] = (_Float16)x1.x; a[5] = (_Float16)x1.y;
      a[6] = (_Float16)x1.z; a[7] = (_Float16)x1.w;
      acc[0] = __builtin_amdgcn_mfma_f32_16x16x32_f16(a, Breg[i][0], acc[0], 0, 0, 0);
      acc[1] = __builtin_amdgcn_mfma_f32_16x16x32_f16(a, Breg[i][1], acc[1], 0, 0, 0);
      acc[2] = __builtin_amdgcn_mfma_f32_16x16x32_f16(a, Breg[i][2], acc[2], 0, 0, 0);
      acc[3] = __builtin_amdgcn_mfma_f32_16x16x32_f16(a, Breg[i][3], acc[3], 0, 0, 0);
    }

    // two-slot partial reduction: waves 0,1 write; waves 2,3 add
    if (w < 2) {
      #pragma unroll
      for (int sub = 0; sub < 4; ++sub)
        #pragma unroll
        for (int r = 0; r < 4; ++r)
          partw[(4 * quad + r) * 66 + sub * 16 + n] = acc[sub][r];
    }
    __syncthreads();
    if (w >= 2) {
      #pragma unroll
      for (int sub = 0; sub < 4; ++sub)
        #pragma unroll
        for (int r = 0; r < 4; ++r)
          partw[(4 * quad + r) * 66 + sub * 16 + n] += acc[sub][r];
    }
    __syncthreads();

    // combine 2 slots; emit q16, qs (f16), |q|^2
    #pragma unroll
    for (int k = 0; k < 4; ++k) {
      int e = tid + k * 256;
      int row = e >> 6, h = e & 63;          // row is wave-uniform
      float s = part[row * 66 + h] + part[1056 + row * 66 + h];
      q16[(size_t)(r0 + row) * 64 + h] = (_Float16)s;
      qs[row * 66 + h] = (_Float16)s;
      float ss = s * s;
      #pragma unroll
      for (int off = 1; off < 64; off <<= 1) ss += __shfl_xor(ss, off);
      if (lane == 0) sumsq[row] = ss;
    }
    __syncthreads();

    if (tid < 16)
      Ct[r0 + tid] = sumsq[tid] * 0.18033688f + b0v + 8.0f;

    // transposed store q16T[b][h][t]
    {
      const int h = tid >> 2, rq = (tid & 3) * 4;
      half4 hv;
      hv[0] = qs[(rq + 0) * 66 + h]; hv[1] = qs[(rq + 1) * 66 + h];
      hv[2] = qs[(rq + 2) * 66 + h]; hv[3] = qs[(rq + 3) * 66 + h];
      const int bb = r0 >> 11, tt = r0 & 2047;
      *(half4*)(q16T + (size_t)(bb * 64 + h) * T_SEQ + tt + rq) = hv;
    }
  }
}

// ---------------------------------------------------------------------------
// Kernel 2: attention, fixed-offset softmax. 512 blocks x 256 thr (4 waves);
// block = (b, pair p): processes q-tiles p and 127-p -> identical total work
// per block (~33 k-tiles) under ANY dispatch mapping. k-split 4 across waves,
// register KV double-buffer, non-atomic 4-way LDS combine per tile.
// ---------------------------------------------------------------------------
__global__ __launch_bounds__(256, 2) void attn_kernel(
    const _Float16* __restrict__ q16, const _Float16* __restrict__ q16T,
    const float* __restrict__ biasS, const float* __restrict__ Ct,
    float* __restrict__ out)
{
  __shared__ __align__(16) _Float16 Pbuf[4 * 16 * 72];  // 9216 B
  __shared__ float Obuf[4 * 16 * 65];                   // 16640 B
  __shared__ float Lbuf[4 * 16];                        // 256 B
  __shared__ float biasL[2080];                         // 8320 B

  const int bi = blockIdx.x;
  const int b  = bi & 7;
  const int p  = bi >> 3;               // [0,64)

  const int tid  = threadIdx.x;
  const int w    = tid >> 6;
  const int lane = tid & 63;
  const int n    = lane & 15, quad = lane >> 4;

  _Float16* Pw = Pbuf + w * 1152;
  const float ksc = 0.125f * 1.44269504f;
  const _Float16* vbase = q16T + (size_t)(b * 64 + n) * T_SEQ + quad * 8;
  const half8 ones = {(_Float16)1, (_Float16)1, (_Float16)1, (_Float16)1,
                      (_Float16)1, (_Float16)1, (_Float16)1, (_Float16)1};

  #define LOAD_KV(S0, K, V)                                                   \
    {                                                                         \
      _Pragma("unroll")                                                       \
      for (int sub = 0; sub < 4; ++sub) {                                     \
        const _Float16* kp =                                                  \
            q16 + (size_t)(b * T_SEQ + (S0) + sub * 16 + n) * 64 + quad * 8;  \
        K[2 * sub]     = *(const half8*)kp;                                   \
        K[2 * sub + 1] = *(const half8*)(kp + 32);                            \
      }                                                                       \
      _Pragma("unroll")                                                       \
      for (int sh = 0; sh < 4; ++sh) {                                        \
        V[sh]     = *(const half8*)(vbase + (size_t)(sh * 16) * T_SEQ + (S0));\
        V[4 + sh] = *(const half8*)(vbase + (size_t)(sh * 16) * T_SEQ + (S0) + 32); \
      }                                                                       \
    }

  #pragma unroll 1
  for (int ht = 0; ht < 2; ++ht) {
    const int qi = ht ? (127 - p) : p;
    const int t0 = qi * 16;
    const int kfull = t0 >> 6;          // tiles [0,kfull) unmasked; kfull = diag

    // stage bias slice (disjoint from Obuf -> safe vs previous combine)
    {
      const int lo = 2032 - t0, cnt = t0 + 31;
      for (int i = tid; i < cnt; i += 256) biasL[i] = biasS[lo + i];
    }

    half8 aq0, aq1;
    {
      const _Float16* qrow = q16 + (size_t)(b * T_SEQ + t0 + n) * 64 + quad * 8;
      aq0 = *(const half8*)qrow;
      aq1 = *(const half8*)(qrow + 32);
    }
    float ctv[4];
    #pragma unroll
    for (int r = 0; r < 4; ++r)
      ctv[r] = Ct[b * T_SEQ + t0 + 4 * quad + r];

    floatx4 O[4];
    #pragma unroll
    for (int s = 0; s < 4; ++s) O[s] = (floatx4){0.f, 0.f, 0.f, 0.f};
    floatx4 den = (floatx4){0.f, 0.f, 0.f, 0.f};

    __syncthreads();   // biasL ready; previous tile fully combined

    half8 cK[8], cV[8], nK[8], nV[8];
    int kt = w;
    if (kt <= kfull) LOAD_KV(kt * 64, cK, cV);

    for (; kt <= kfull; kt += 4) {
      const int ktn = kt + 4;
      if (ktn <= kfull) LOAD_KV(ktn * 64, nK, nV);

      const int  s0 = kt * 64;
      const bool dg = (kt == kfull);
      const int  j  = (t0 - s0) >> 4;   // valid when dg

      #pragma unroll
      for (int sub = 0; sub < 4; ++sub) {
        if (dg && sub > j) {
          #pragma unroll
          for (int r = 0; r < 4; ++r)
            Pw[(4 * quad + r) * 72 + sub * 16 + n] = (_Float16)0.f;
          continue;
        }
        floatx4 sc = (floatx4){0.f, 0.f, 0.f, 0.f};
        sc = __builtin_amdgcn_mfma_f32_16x16x32_f16(aq0, cK[2 * sub], sc, 0, 0, 0);
        sc = __builtin_amdgcn_mfma_f32_16x16x32_f16(aq1, cK[2 * sub + 1], sc, 0, 0, 0);
        const int smin = s0 + sub * 16;
        #pragma unroll
        for (int r = 0; r < 4; ++r) {
          float bv = biasL[15 + smin + n - 4 * quad - r];
          float pv = exp2f(fmaf(sc[r], ksc, bv) - ctv[r]);
          if (dg && sub == j && n > 4 * quad + r) pv = 0.f;  // causal diagonal
          Pw[(4 * quad + r) * 72 + sub * 16 + n] = (_Float16)pv;
        }
      }

      #pragma unroll
      for (int ch = 0; ch < 2; ++ch) {
        half8 pf = *(const half8*)(Pw + n * 72 + ch * 32 + quad * 8);
        den = __builtin_amdgcn_mfma_f32_16x16x32_f16(pf, ones, den, 0, 0, 0);
        #pragma unroll
        for (int sh = 0; sh < 4; ++sh)
          O[sh] = __builtin_amdgcn_mfma_f32_16x16x32_f16(pf, cV[ch * 4 + sh],
                                                         O[sh], 0, 0, 0);
      }

      #pragma unroll
      for (int i = 0; i < 8; ++i) { cK[i] = nK[i]; cV[i] = nV[i]; }
    }

    // per-wave partials
    #pragma unroll
    for (int sub = 0; sub < 4; ++sub)
      #pragma unroll
      for (int r = 0; r < 4; ++r)
        Obuf[w * 1040 + (4 * quad + r) * 65 + sub * 16 + n] = O[sub][r];
    if (n == 0) {
      #pragma unroll
      for (int r = 0; r < 4; ++r)
        Lbuf[w * 16 + 4 * quad + r] = den[r];
    }
    __syncthreads();

    // 4-way combine + output
    #pragma unroll
    for (int k = 0; k < 4; ++k) {
      const int e = tid + k * 256;
      const int row = e >> 6, h = e & 63;
      float num = Obuf[row * 65 + h]        + Obuf[1040 + row * 65 + h] +
                  Obuf[2080 + row * 65 + h] + Obuf[3120 + row * 65 + h];
      float d   = Lbuf[row] + Lbuf[16 + row] + Lbuf[32 + row] + Lbuf[48 + row];
      out[(size_t)(b * T_SEQ + t0 + row) * 64 + h] = num / d;
    }
  }
  #undef LOAD_KV
}

// ---------------------------------------------------------------------------
extern "C" void kernel_launch(void* const* d_in, const int* in_sizes, int n_in,
                              void* d_out, int out_size, void* d_ws, size_t ws_size,
                              hipStream_t stream) {
  const float* x   = (const float*)d_in[0];
  const float* Wq  = (const float*)d_in[1];
  const float* rel = (const float*)d_in[2];
  float* out = (float*)d_out;

  _Float16* q16   = (_Float16*)d_ws;                    // [8][2048][64]
  _Float16* q16T  = q16  + (size_t)NB * T_SEQ * 64;     // [8][64][2048]
  _Float16* WqT   = q16T + (size_t)NB * T_SEQ * 64;     // [64][768]
  float*    biasS = (float*)(WqT + 64 * 768);           // [4095] (+pad)
  float*    Ct    = biasS + 4096;                       // [16384]

  prep_kernel <<<65,  256, 0, stream>>>(Wq, rel, WqT, biasS);
  qproj_kernel<<<512, 256, 0, stream>>>(x, WqT, rel, q16, q16T, Ct);
  attn_kernel <<<512, 256, 0, stream>>>(q16, q16T, biasS, Ct, out);
}